// Round 5
// baseline (492.829 us; speedup 1.0000x reference)
//
#include <hip/hip_runtime.h>

#define VN     5023
#define NBETA  150
#define NBP    152          // padded K (multiple of 8, float4-aligned rows)
#define NBATCH 1024
#define N3     15069        // V*3
#define BT     32           // batches per block in K3

// ---------------- K0: pad shapedirs rows 150 -> 152 (zeros), f32 ----------------
__global__ void k0_pad(const float* __restrict__ sd, float* __restrict__ sdp) {
    int i = blockIdx.x * 256 + threadIdx.x;          // over V*3*NBP
    if (i >= VN * 3 * NBP) return;
    int row = i / NBP, l = i - row * NBP;
    sdp[i] = (l < NBETA) ? sd[row * NBETA + l] : 0.0f;
}

// ---------------- K1a: JS[j,c,l] = sum_v jr[j,v] * sd[v,c,l]  (atomic partials) --------
__global__ void k1_js(const float* __restrict__ jr, const float* __restrict__ sdp,
                      float* __restrict__ JS) {
    int j3c = blockIdx.x;              // 0..14
    int chunk = blockIdx.y;            // 0..31
    int j = j3c / 3, c = j3c - 3 * j;
    int l = threadIdx.x;
    if (l >= NBP) return;
    int v0 = chunk * 157, v1 = min(v0 + 157, VN);
    float acc = 0.0f;
    for (int v = v0; v < v1; ++v) {
        acc += jr[j * VN + v] * sdp[(v * 3 + c) * NBP + l];
    }
    atomicAdd(&JS[j3c * NBP + l], acc);
}

// ---------------- K1b: Jt[j,c] = sum_v jr[j,v] * v_template[v,c] ----------------------
__global__ void k1_jt(const float* __restrict__ jr, const float* __restrict__ vt,
                      float* __restrict__ Jt) {
    int j3c = blockIdx.x;
    int j = j3c / 3, c = j3c - 3 * j;
    int t = threadIdx.x;
    __shared__ float red[256];
    float acc = 0.0f;
    for (int v = t; v < VN; v += 256) acc += jr[j * VN + v] * vt[v * 3 + c];
    red[t] = acc; __syncthreads();
    for (int s = 128; s > 0; s >>= 1) { if (t < s) red[t] += red[t + s]; __syncthreads(); }
    if (t == 0) Jt[j3c] = red[0];
}

// ---------------- rodrigues (matches reference eps semantics) -------------------------
__device__ __forceinline__ void rodrigues3(float x, float y, float z, float* R) {
    float ax = x + 1e-8f, ay = y + 1e-8f, az = z + 1e-8f;
    float ang = sqrtf(ax * ax + ay * ay + az * az);
    float inv = 1.0f / ang;
    float ux = x * inv, uy = y * inv, uz = z * inv;
    float co = cosf(ang), si = sinf(ang), t1 = 1.0f - co;
    float K[9] = {0.f, -uz, uy,  uz, 0.f, -ux,  -uy, ux, 0.f};
    float K2[9];
#pragma unroll
    for (int r = 0; r < 3; r++)
#pragma unroll
        for (int cc = 0; cc < 3; cc++) {
            float a = 0.f;
#pragma unroll
            for (int k = 0; k < 3; k++) a += K[r * 3 + k] * K[k * 3 + cc];
            K2[r * 3 + cc] = a;
        }
#pragma unroll
    for (int i = 0; i < 9; i++) {
        float e = (i == 0 || i == 4 || i == 8) ? 1.f : 0.f;
        R[i] = e + si * K[i] + t1 * K2[i];
    }
}

// ---------------- K2: per-batch betas (padded), joints, chain, rel_transforms, pf9 ----
__global__ void k2_pose(const float* __restrict__ shp, const float* __restrict__ expr,
                        const float* __restrict__ pose, const float* __restrict__ JS,
                        const float* __restrict__ Jt, float* __restrict__ betasF,
                        float* __restrict__ pf9, float* __restrict__ rel) {
    int b = blockIdx.x;
    int tt = threadIdx.x;
    __shared__ float sB[NBP];
    __shared__ float sJ[15];
    for (int l = tt; l < NBP; l += 64) {
        float val = 0.0f;
        if (l < 100) val = shp[b * 100 + l];
        else if (l < 150) val = expr[b * 50 + (l - 100)];
        sB[l] = val;
        betasF[b * NBP + l] = val;
    }
    __syncthreads();
    if (tt < 15) {
        float acc = Jt[tt];
        const float* row = JS + tt * NBP;
        for (int l = 0; l < NBETA; ++l) acc += row[l] * sB[l];
        sJ[tt] = acc;
    }
    __syncthreads();
    if (tt == 0) {
        float p[6];
#pragma unroll
        for (int i = 0; i < 6; i++) p[i] = pose[b * 6 + i];
        float R0[9], RJ[9];
        rodrigues3(p[0], p[1], p[2], R0);
        rodrigues3(p[3], p[4], p[5], RJ);
        float Jm[5][3];
#pragma unroll
        for (int jj = 0; jj < 5; jj++)
#pragma unroll
            for (int cc = 0; cc < 3; cc++) Jm[jj][cc] = sJ[jj * 3 + cc];
        float rj[5][3];
#pragma unroll
        for (int cc = 0; cc < 3; cc++) {
            rj[0][cc] = Jm[0][cc];
            rj[1][cc] = Jm[1][cc] - Jm[0][cc];
            rj[2][cc] = Jm[2][cc] - Jm[1][cc];
            rj[3][cc] = Jm[3][cc] - Jm[1][cc];
            rj[4][cc] = Jm[4][cc] - Jm[1][cc];
        }
        // world translations: tw0 = J0; tw1 = R0*rj1 + tw0; twj = R0*rjj + tw1 (j>=2)
        float tw[5][3];
#pragma unroll
        for (int cc = 0; cc < 3; cc++) tw[0][cc] = rj[0][cc];
#pragma unroll
        for (int cc = 0; cc < 3; cc++)
            tw[1][cc] = R0[cc * 3 + 0] * rj[1][0] + R0[cc * 3 + 1] * rj[1][1] + R0[cc * 3 + 2] * rj[1][2] + tw[0][cc];
#pragma unroll
        for (int jj = 2; jj < 5; jj++)
#pragma unroll
            for (int cc = 0; cc < 3; cc++)
                tw[jj][cc] = R0[cc * 3 + 0] * rj[jj][0] + R0[cc * 3 + 1] * rj[jj][1] + R0[cc * 3 + 2] * rj[jj][2] + tw[1][cc];
        // jaw world rotation
        float R2w[9];
#pragma unroll
        for (int r = 0; r < 3; r++)
#pragma unroll
            for (int cc = 0; cc < 3; cc++) {
                float a = 0.f;
#pragma unroll
                for (int k = 0; k < 3; k++) a += R0[r * 3 + k] * RJ[k * 3 + cc];
                R2w[r * 3 + cc] = a;
            }
        float* ro = rel + b * 80;
#pragma unroll
        for (int jj = 0; jj < 5; jj++) {
            const float* Rw = (jj == 2) ? R2w : R0;
#pragma unroll
            for (int rr = 0; rr < 3; rr++) {
                ro[jj * 16 + rr * 4 + 0] = Rw[rr * 3 + 0];
                ro[jj * 16 + rr * 4 + 1] = Rw[rr * 3 + 1];
                ro[jj * 16 + rr * 4 + 2] = Rw[rr * 3 + 2];
                float tj = Rw[rr * 3 + 0] * Jm[jj][0] + Rw[rr * 3 + 1] * Jm[jj][1] + Rw[rr * 3 + 2] * Jm[jj][2];
                ro[jj * 16 + rr * 4 + 3] = tw[jj][rr] - tj;
            }
            ro[jj * 16 + 12] = 0.f; ro[jj * 16 + 13] = 0.f; ro[jj * 16 + 14] = 0.f; ro[jj * 16 + 15] = 1.f;
        }
        // jaw pose feature (only nonzero block of pose_feature)
        float* pf = pf9 + b * 12;
#pragma unroll
        for (int e = 0; e < 9; e++) pf[e] = RJ[e] - ((e == 0 || e == 4 || e == 8) ? 1.f : 0.f);
        pf[9] = 0.f; pf[10] = 0.f; pf[11] = 0.f;
    }
}

// ---------------- K3: fused blendshape GEMM + pose blend + LBS ------------------------
__global__ void k3_main(const float* __restrict__ sdp, const float* __restrict__ pd,
                        const float* __restrict__ vt, const float* __restrict__ lw,
                        const float* __restrict__ betasF, const float* __restrict__ pf9,
                        const float* __restrict__ rel,
                        float* __restrict__ outv, float* __restrict__ outT) {
    int tid = threadIdx.x;
    int v = blockIdx.x * 128 + tid;
    bool ok = v < VN;
    int vc = ok ? v : 0;
    int b0 = blockIdx.y * BT;

    float acc[3][BT];
#pragma unroll
    for (int c = 0; c < 3; c++)
#pragma unroll
        for (int bb = 0; bb < BT; bb++) acc[c][bb] = 0.0f;

    const float* srow = sdp + (size_t)vc * 3 * NBP;
    const float* bbase = betasF + (size_t)b0 * NBP;

#pragma unroll 1
    for (int l0 = 0; l0 < NBP; l0 += 8) {
        float s[3][8];
#pragma unroll
        for (int c = 0; c < 3; c++) {
            const float4 r0 = *(const float4*)(srow + c * NBP + l0);
            const float4 r1 = *(const float4*)(srow + c * NBP + l0 + 4);
            s[c][0] = r0.x; s[c][1] = r0.y; s[c][2] = r0.z; s[c][3] = r0.w;
            s[c][4] = r1.x; s[c][5] = r1.y; s[c][6] = r1.z; s[c][7] = r1.w;
        }
#pragma unroll
        for (int bb = 0; bb < BT; bb++) {
            const float* bp = bbase + bb * NBP + l0;
            const float4 be0 = *(const float4*)(bp);
            const float4 be1 = *(const float4*)(bp + 4);
            float be[8] = {be0.x, be0.y, be0.z, be0.w, be1.x, be1.y, be1.z, be1.w};
#pragma unroll
            for (int k = 0; k < 8; k++) {
                acc[0][bb] += be[k] * s[0][k];
                acc[1][bb] += be[k] * s[1][k];
                acc[2][bb] += be[k] * s[2][k];
            }
        }
    }

    if (!ok) return;

    float vtv[3], wj[5], pdv[9][3];
#pragma unroll
    for (int c = 0; c < 3; c++) vtv[c] = vt[v * 3 + c];
#pragma unroll
    for (int j = 0; j < 5; j++) wj[j] = lw[v * 5 + j];
#pragma unroll
    for (int k = 0; k < 9; k++)
#pragma unroll
        for (int c = 0; c < 3; c++) pdv[k][c] = pd[(size_t)(9 + k) * N3 + v * 3 + c];

#pragma unroll
    for (int bb = 0; bb < BT; bb++) {
        int b = b0 + bb;
        const float* rb = rel + b * 80;
        const float* pf = pf9 + b * 12;
        float vp[3];
#pragma unroll
        for (int c = 0; c < 3; c++) {
            float x = vtv[c] + acc[c][bb];
#pragma unroll
            for (int k = 0; k < 9; k++) x += pf[k] * pdv[k][c];
            vp[c] = x;
        }
        float T[16];
#pragma unroll
        for (int e = 0; e < 16; e++) {
            float x = wj[0] * rb[e];
#pragma unroll
            for (int j = 1; j < 5; j++) x += wj[j] * rb[j * 16 + e];
            T[e] = x;
        }
        float vo[3];
#pragma unroll
        for (int rr = 0; rr < 3; rr++)
            vo[rr] = T[rr * 4 + 0] * vp[0] + T[rr * 4 + 1] * vp[1] + T[rr * 4 + 2] * vp[2] + T[rr * 4 + 3];

        size_t vbase = (size_t)b * VN + v;
        float* pv = outv + vbase * 3;
        pv[0] = vo[0];
        pv[1] = vo[1];
        pv[2] = vo[2];
        float4* pT = (float4*)(outT + vbase * 16);
        pT[0] = make_float4(T[0],  T[1],  T[2],  T[3]);
        pT[1] = make_float4(T[4],  T[5],  T[6],  T[7]);
        pT[2] = make_float4(T[8],  T[9],  T[10], T[11]);
        pT[3] = make_float4(T[12], T[13], T[14], T[15]);
    }
}

// ---------------- launch ----------------
extern "C" void kernel_launch(void* const* d_in, const int* in_sizes, int n_in,
                              void* d_out, int out_size, void* d_ws, size_t ws_size,
                              hipStream_t stream) {
    const float* shp  = (const float*)d_in[0];  // [1024,100]
    const float* expr = (const float*)d_in[1];  // [1024,50]
    const float* pose = (const float*)d_in[2];  // [1024,6]
    const float* vt   = (const float*)d_in[3];  // [5023,3]
    const float* sd   = (const float*)d_in[4];  // [5023,3,150]
    const float* pd   = (const float*)d_in[5];  // [36,15069]
    const float* jr   = (const float*)d_in[6];  // [5,5023]
    const float* lw   = (const float*)d_in[7];  // [5023,5]

    float* outv = (float*)d_out;
    float* outT = outv + (size_t)NBATCH * VN * 3;

    char* w = (char*)d_ws;
    const size_t SDP_B   = (size_t)VN * 3 * NBP * 4;        // 9,161,952
    const size_t JS_B    = 15 * NBP * 4;                    // 9,120
    const size_t JT_B    = 64;
    const size_t BETAS_B = (size_t)NBATCH * NBP * 4;        // 622,592
    const size_t PF9_B   = (size_t)NBATCH * 12 * 4;         // 49,152
    float* sdp    = (float*)w;
    float* JS     = (float*)(w + SDP_B);
    float* Jt     = (float*)(w + SDP_B + JS_B);
    float* betasF = (float*)(w + SDP_B + JS_B + JT_B);
    float* pf9    = (float*)(w + SDP_B + JS_B + JT_B + BETAS_B);
    float* rel    = (float*)(w + SDP_B + JS_B + JT_B + BETAS_B + PF9_B);

    hipMemsetAsync(JS, 0, JS_B + JT_B, stream);
    k0_pad<<<(VN * 3 * NBP + 255) / 256, 256, 0, stream>>>(sd, sdp);
    k1_js<<<dim3(15, 32), 192, 0, stream>>>(jr, sdp, JS);
    k1_jt<<<15, 256, 0, stream>>>(jr, vt, Jt);
    k2_pose<<<NBATCH, 64, 0, stream>>>(shp, expr, pose, JS, Jt, betasF, pf9, rel);
    k3_main<<<dim3(40, 32), 128, 0, stream>>>(sdp, pd, vt, lw, betasF, pf9, rel, outv, outT);
}

// Round 6
// 307.006 us; speedup vs baseline: 1.6053x; 1.6053x over previous
//
#include <hip/hip_runtime.h>

#define VN     5023
#define NBETA  150
#define NBP    152          // padded K (multiple of 8, float4-aligned rows)
#define NBATCH 1024
#define N3     15069        // V*3
#define BT     16           // batches per block in K3 (was 32: occupancy-limited)

// ---------------- K0: pad shapedirs rows 150 -> 152 (zeros), f32 ----------------
__global__ void k0_pad(const float* __restrict__ sd, float* __restrict__ sdp) {
    int i = blockIdx.x * 256 + threadIdx.x;          // over V*3*NBP
    if (i >= VN * 3 * NBP) return;
    int row = i / NBP, l = i - row * NBP;
    sdp[i] = (l < NBETA) ? sd[row * NBETA + l] : 0.0f;
}

// ---------------- K1a: JS[j,c,l] = sum_v jr[j,v] * sd[v,c,l]  (atomic partials) --------
__global__ void k1_js(const float* __restrict__ jr, const float* __restrict__ sdp,
                      float* __restrict__ JS) {
    int j3c = blockIdx.x;              // 0..14
    int chunk = blockIdx.y;            // 0..31
    int j = j3c / 3, c = j3c - 3 * j;
    int l = threadIdx.x;
    if (l >= NBP) return;
    int v0 = chunk * 157, v1 = min(v0 + 157, VN);
    float acc = 0.0f;
    for (int v = v0; v < v1; ++v) {
        acc += jr[j * VN + v] * sdp[(v * 3 + c) * NBP + l];
    }
    atomicAdd(&JS[j3c * NBP + l], acc);
}

// ---------------- K1b: Jt[j,c] = sum_v jr[j,v] * v_template[v,c] ----------------------
__global__ void k1_jt(const float* __restrict__ jr, const float* __restrict__ vt,
                      float* __restrict__ Jt) {
    int j3c = blockIdx.x;
    int j = j3c / 3, c = j3c - 3 * j;
    int t = threadIdx.x;
    __shared__ float red[256];
    float acc = 0.0f;
    for (int v = t; v < VN; v += 256) acc += jr[j * VN + v] * vt[v * 3 + c];
    red[t] = acc; __syncthreads();
    for (int s = 128; s > 0; s >>= 1) { if (t < s) red[t] += red[t + s]; __syncthreads(); }
    if (t == 0) Jt[j3c] = red[0];
}

// ---------------- rodrigues (matches reference eps semantics) -------------------------
__device__ __forceinline__ void rodrigues3(float x, float y, float z, float* R) {
    float ax = x + 1e-8f, ay = y + 1e-8f, az = z + 1e-8f;
    float ang = sqrtf(ax * ax + ay * ay + az * az);
    float inv = 1.0f / ang;
    float ux = x * inv, uy = y * inv, uz = z * inv;
    float co = cosf(ang), si = sinf(ang), t1 = 1.0f - co;
    float K[9] = {0.f, -uz, uy,  uz, 0.f, -ux,  -uy, ux, 0.f};
    float K2[9];
#pragma unroll
    for (int r = 0; r < 3; r++)
#pragma unroll
        for (int cc = 0; cc < 3; cc++) {
            float a = 0.f;
#pragma unroll
            for (int k = 0; k < 3; k++) a += K[r * 3 + k] * K[k * 3 + cc];
            K2[r * 3 + cc] = a;
        }
#pragma unroll
    for (int i = 0; i < 9; i++) {
        float e = (i == 0 || i == 4 || i == 8) ? 1.f : 0.f;
        R[i] = e + si * K[i] + t1 * K2[i];
    }
}

// ---------------- K2: per-batch betas (padded), joints, chain, rel_transforms, pf9 ----
__global__ void k2_pose(const float* __restrict__ shp, const float* __restrict__ expr,
                        const float* __restrict__ pose, const float* __restrict__ JS,
                        const float* __restrict__ Jt, float* __restrict__ betasF,
                        float* __restrict__ pf9, float* __restrict__ rel) {
    int b = blockIdx.x;
    int tt = threadIdx.x;
    __shared__ float sB[NBP];
    __shared__ float sJ[15];
    for (int l = tt; l < NBP; l += 64) {
        float val = 0.0f;
        if (l < 100) val = shp[b * 100 + l];
        else if (l < 150) val = expr[b * 50 + (l - 100)];
        sB[l] = val;
        betasF[b * NBP + l] = val;
    }
    __syncthreads();
    if (tt < 15) {
        float acc = Jt[tt];
        const float* row = JS + tt * NBP;
        for (int l = 0; l < NBETA; ++l) acc += row[l] * sB[l];
        sJ[tt] = acc;
    }
    __syncthreads();
    if (tt == 0) {
        float p[6];
#pragma unroll
        for (int i = 0; i < 6; i++) p[i] = pose[b * 6 + i];
        float R0[9], RJ[9];
        rodrigues3(p[0], p[1], p[2], R0);
        rodrigues3(p[3], p[4], p[5], RJ);
        float Jm[5][3];
#pragma unroll
        for (int jj = 0; jj < 5; jj++)
#pragma unroll
            for (int cc = 0; cc < 3; cc++) Jm[jj][cc] = sJ[jj * 3 + cc];
        float rj[5][3];
#pragma unroll
        for (int cc = 0; cc < 3; cc++) {
            rj[0][cc] = Jm[0][cc];
            rj[1][cc] = Jm[1][cc] - Jm[0][cc];
            rj[2][cc] = Jm[2][cc] - Jm[1][cc];
            rj[3][cc] = Jm[3][cc] - Jm[1][cc];
            rj[4][cc] = Jm[4][cc] - Jm[1][cc];
        }
        float tw[5][3];
#pragma unroll
        for (int cc = 0; cc < 3; cc++) tw[0][cc] = rj[0][cc];
#pragma unroll
        for (int cc = 0; cc < 3; cc++)
            tw[1][cc] = R0[cc * 3 + 0] * rj[1][0] + R0[cc * 3 + 1] * rj[1][1] + R0[cc * 3 + 2] * rj[1][2] + tw[0][cc];
#pragma unroll
        for (int jj = 2; jj < 5; jj++)
#pragma unroll
            for (int cc = 0; cc < 3; cc++)
                tw[jj][cc] = R0[cc * 3 + 0] * rj[jj][0] + R0[cc * 3 + 1] * rj[jj][1] + R0[cc * 3 + 2] * rj[jj][2] + tw[1][cc];
        float R2w[9];
#pragma unroll
        for (int r = 0; r < 3; r++)
#pragma unroll
            for (int cc = 0; cc < 3; cc++) {
                float a = 0.f;
#pragma unroll
                for (int k = 0; k < 3; k++) a += R0[r * 3 + k] * RJ[k * 3 + cc];
                R2w[r * 3 + cc] = a;
            }
        float* ro = rel + b * 80;
#pragma unroll
        for (int jj = 0; jj < 5; jj++) {
            const float* Rw = (jj == 2) ? R2w : R0;
#pragma unroll
            for (int rr = 0; rr < 3; rr++) {
                ro[jj * 16 + rr * 4 + 0] = Rw[rr * 3 + 0];
                ro[jj * 16 + rr * 4 + 1] = Rw[rr * 3 + 1];
                ro[jj * 16 + rr * 4 + 2] = Rw[rr * 3 + 2];
                float tj = Rw[rr * 3 + 0] * Jm[jj][0] + Rw[rr * 3 + 1] * Jm[jj][1] + Rw[rr * 3 + 2] * Jm[jj][2];
                ro[jj * 16 + rr * 4 + 3] = tw[jj][rr] - tj;
            }
            ro[jj * 16 + 12] = 0.f; ro[jj * 16 + 13] = 0.f; ro[jj * 16 + 14] = 0.f; ro[jj * 16 + 15] = 1.f;
        }
        float* pf = pf9 + b * 12;
#pragma unroll
        for (int e = 0; e < 9; e++) pf[e] = RJ[e] - ((e == 0 || e == 4 || e == 8) ? 1.f : 0.f);
        pf[9] = 0.f; pf[10] = 0.f; pf[11] = 0.f;
    }
}

// ---------------- K3: fused blendshape GEMM + pose blend + LBS ------------------------
// Block: 128 threads (one vertex each), BT=16 batches. Uniform per-batch data
// (betas, rel, pf9) staged once into LDS; inner-loop reads are same-address
// broadcasts (no bank conflicts). LDS = 15.5 KB -> 10 blocks/CU -> 20 waves/CU.
__global__ void k3_main(const float* __restrict__ sdp, const float* __restrict__ pd,
                        const float* __restrict__ vt, const float* __restrict__ lw,
                        const float* __restrict__ betasF, const float* __restrict__ pf9,
                        const float* __restrict__ rel,
                        float* __restrict__ outv, float* __restrict__ outT) {
    __shared__ float sBet[BT][NBP];   // 16*152*4 = 9728 B (rows 608B: 16B-aligned)
    __shared__ float sRel[BT][80];    // 5120 B
    __shared__ float sPf[BT][12];     // 768 B

    int tid = threadIdx.x;
    int v = blockIdx.x * 128 + tid;
    bool ok = v < VN;
    int vc = ok ? v : 0;
    int b0 = blockIdx.y * BT;

    // cooperative coalesced staging of block-uniform data
    for (int i = tid; i < BT * NBP; i += 128) {
        int bb = i / NBP, l = i - bb * NBP;
        sBet[bb][l] = betasF[(size_t)(b0 + bb) * NBP + l];
    }
    for (int i = tid; i < BT * 80; i += 128) {
        int bb = i / 80, e = i - bb * 80;
        sRel[bb][e] = rel[(size_t)(b0 + bb) * 80 + e];
    }
    for (int i = tid; i < BT * 12; i += 128) {
        int bb = i / 12, e = i - bb * 12;
        sPf[bb][e] = pf9[(size_t)(b0 + bb) * 12 + e];
    }
    __syncthreads();

    float acc[3][BT];
#pragma unroll
    for (int c = 0; c < 3; c++)
#pragma unroll
        for (int bb = 0; bb < BT; bb++) acc[c][bb] = 0.0f;

    const float* srow = sdp + (size_t)vc * 3 * NBP;

#pragma unroll 1
    for (int l0 = 0; l0 < NBP; l0 += 8) {
        float s[3][8];
#pragma unroll
        for (int c = 0; c < 3; c++) {
            const float4 r0 = *(const float4*)(srow + c * NBP + l0);
            const float4 r1 = *(const float4*)(srow + c * NBP + l0 + 4);
            s[c][0] = r0.x; s[c][1] = r0.y; s[c][2] = r0.z; s[c][3] = r0.w;
            s[c][4] = r1.x; s[c][5] = r1.y; s[c][6] = r1.z; s[c][7] = r1.w;
        }
#pragma unroll
        for (int bb = 0; bb < BT; bb++) {
            const float4 be0 = *(const float4*)(&sBet[bb][l0]);
            const float4 be1 = *(const float4*)(&sBet[bb][l0 + 4]);
            float be[8] = {be0.x, be0.y, be0.z, be0.w, be1.x, be1.y, be1.z, be1.w};
#pragma unroll
            for (int k = 0; k < 8; k++) {
                acc[0][bb] += be[k] * s[0][k];
                acc[1][bb] += be[k] * s[1][k];
                acc[2][bb] += be[k] * s[2][k];
            }
        }
    }

    if (!ok) return;   // after all __syncthreads

    float vtv[3], wj[5], pdv[9][3];
#pragma unroll
    for (int c = 0; c < 3; c++) vtv[c] = vt[v * 3 + c];
#pragma unroll
    for (int j = 0; j < 5; j++) wj[j] = lw[v * 5 + j];
#pragma unroll
    for (int k = 0; k < 9; k++)
#pragma unroll
        for (int c = 0; c < 3; c++) pdv[k][c] = pd[(size_t)(9 + k) * N3 + v * 3 + c];

#pragma unroll    // full unroll: acc[c][bb] must stay register-indexed (no scratch)
    for (int bb = 0; bb < BT; bb++) {
        int b = b0 + bb;
        float vp[3];
#pragma unroll
        for (int c = 0; c < 3; c++) {
            float x = vtv[c] + acc[c][bb];
#pragma unroll
            for (int k = 0; k < 9; k++) x += sPf[bb][k] * pdv[k][c];
            vp[c] = x;
        }
        float T[16];
#pragma unroll
        for (int e = 0; e < 16; e++) T[e] = 0.0f;
#pragma unroll
        for (int j = 0; j < 5; j++) {
            float w = wj[j];
            const float4* rj4 = (const float4*)(&sRel[bb][j * 16]);
            float4 r0 = rj4[0], r1 = rj4[1], r2 = rj4[2], r3 = rj4[3];
            T[0]  += w * r0.x;  T[1]  += w * r0.y;  T[2]  += w * r0.z;  T[3]  += w * r0.w;
            T[4]  += w * r1.x;  T[5]  += w * r1.y;  T[6]  += w * r1.z;  T[7]  += w * r1.w;
            T[8]  += w * r2.x;  T[9]  += w * r2.y;  T[10] += w * r2.z;  T[11] += w * r2.w;
            T[12] += w * r3.x;  T[13] += w * r3.y;  T[14] += w * r3.z;  T[15] += w * r3.w;
        }
        float vo[3];
#pragma unroll
        for (int rr = 0; rr < 3; rr++)
            vo[rr] = T[rr * 4 + 0] * vp[0] + T[rr * 4 + 1] * vp[1] + T[rr * 4 + 2] * vp[2] + T[rr * 4 + 3];

        size_t vbase = (size_t)b * VN + v;
        float* pv = outv + vbase * 3;
        pv[0] = vo[0];
        pv[1] = vo[1];
        pv[2] = vo[2];
        float4* pT = (float4*)(outT + vbase * 16);
        pT[0] = make_float4(T[0],  T[1],  T[2],  T[3]);
        pT[1] = make_float4(T[4],  T[5],  T[6],  T[7]);
        pT[2] = make_float4(T[8],  T[9],  T[10], T[11]);
        pT[3] = make_float4(T[12], T[13], T[14], T[15]);
    }
}

// ---------------- launch ----------------
extern "C" void kernel_launch(void* const* d_in, const int* in_sizes, int n_in,
                              void* d_out, int out_size, void* d_ws, size_t ws_size,
                              hipStream_t stream) {
    const float* shp  = (const float*)d_in[0];  // [1024,100]
    const float* expr = (const float*)d_in[1];  // [1024,50]
    const float* pose = (const float*)d_in[2];  // [1024,6]
    const float* vt   = (const float*)d_in[3];  // [5023,3]
    const float* sd   = (const float*)d_in[4];  // [5023,3,150]
    const float* pd   = (const float*)d_in[5];  // [36,15069]
    const float* jr   = (const float*)d_in[6];  // [5,5023]
    const float* lw   = (const float*)d_in[7];  // [5023,5]

    float* outv = (float*)d_out;
    float* outT = outv + (size_t)NBATCH * VN * 3;

    char* w = (char*)d_ws;
    const size_t SDP_B   = (size_t)VN * 3 * NBP * 4;        // 9,161,952
    const size_t JS_B    = 15 * NBP * 4;                    // 9,120
    const size_t JT_B    = 64;
    const size_t BETAS_B = (size_t)NBATCH * NBP * 4;        // 622,592
    const size_t PF9_B   = (size_t)NBATCH * 12 * 4;         // 49,152
    float* sdp    = (float*)w;
    float* JS     = (float*)(w + SDP_B);
    float* Jt     = (float*)(w + SDP_B + JS_B);
    float* betasF = (float*)(w + SDP_B + JS_B + JT_B);
    float* pf9    = (float*)(w + SDP_B + JS_B + JT_B + BETAS_B);
    float* rel    = (float*)(w + SDP_B + JS_B + JT_B + BETAS_B + PF9_B);

    hipMemsetAsync(JS, 0, JS_B + JT_B, stream);
    k0_pad<<<(VN * 3 * NBP + 255) / 256, 256, 0, stream>>>(sd, sdp);
    k1_js<<<dim3(15, 32), 192, 0, stream>>>(jr, sdp, JS);
    k1_jt<<<15, 256, 0, stream>>>(jr, vt, Jt);
    k2_pose<<<NBATCH, 64, 0, stream>>>(shp, expr, pose, JS, Jt, betasF, pf9, rel);
    k3_main<<<dim3(40, NBATCH / BT), 128, 0, stream>>>(sdp, pd, vt, lw, betasF, pf9, rel, outv, outT);
}

// Round 7
// 266.916 us; speedup vs baseline: 1.8464x; 1.1502x over previous
//
#include <hip/hip_runtime.h>

#define VN     5023
#define NBETA  150
#define NBP    152          // padded K: 0..149 betas-dirs, 150 = v_template, 151 = 0
#define NBATCH 1024
#define N3     15069        // V*3
#define BT     16           // batches per block in K3
#define K1_CHUNK 40

// ---- K0: build sdp[N3][NBP] (cols 0..149 = shapedirs, col 150 = v_template, 151 = 0);
//      also zero JS (first 15*NBP threads). k1_js runs after -> ordering safe.
__global__ void k0_pad(const float* __restrict__ sd, const float* __restrict__ vt,
                       float* __restrict__ sdp, float* __restrict__ JS) {
    int i = blockIdx.x * 256 + threadIdx.x;
    if (i < 15 * NBP) JS[i] = 0.0f;
    if (i >= N3 * NBP) return;
    int row = i / NBP, l = i - row * NBP;
    float val = 0.0f;
    if (l < NBETA) val = sd[row * NBETA + l];
    else if (l == NBETA) val = vt[row];   // v_template folded into column 150
    sdp[i] = val;
}

// ---- K1: JS[j3c][l] += sum_v jr[j,v] * sdp[v*3+c][l]  (col 150 gives Jt for free)
__global__ void k1_js(const float* __restrict__ jr, const float* __restrict__ sdp,
                      float* __restrict__ JS) {
    int j3c = blockIdx.x;              // 0..14
    int j = j3c / 3, c = j3c - 3 * j;
    int l = threadIdx.x;
    if (l >= NBP) return;
    int v0 = blockIdx.y * K1_CHUNK, v1 = min(v0 + K1_CHUNK, VN);
    float acc = 0.0f;
    for (int v = v0; v < v1; ++v)
        acc += jr[j * VN + v] * sdp[(size_t)(v * 3 + c) * NBP + l];
    atomicAdd(&JS[j3c * NBP + l], acc);
}

// ---- rodrigues (matches reference eps semantics) ----
__device__ __forceinline__ void rodrigues3(float x, float y, float z, float* R) {
    float ax = x + 1e-8f, ay = y + 1e-8f, az = z + 1e-8f;
    float ang = sqrtf(ax * ax + ay * ay + az * az);
    float inv = 1.0f / ang;
    float ux = x * inv, uy = y * inv, uz = z * inv;
    float co = cosf(ang), si = sinf(ang), t1 = 1.0f - co;
    float K[9] = {0.f, -uz, uy,  uz, 0.f, -ux,  -uy, ux, 0.f};
    float K2[9];
#pragma unroll
    for (int r = 0; r < 3; r++)
#pragma unroll
        for (int cc = 0; cc < 3; cc++) {
            float a = 0.f;
#pragma unroll
            for (int k = 0; k < 3; k++) a += K[r * 3 + k] * K[k * 3 + cc];
            K2[r * 3 + cc] = a;
        }
#pragma unroll
    for (int i = 0; i < 9; i++) {
        float e = (i == 0 || i == 4 || i == 8) ? 1.f : 0.f;
        R[i] = e + si * K[i] + t1 * K2[i];
    }
}

// ---- K2: per-batch betas (col150=1, col151=0), joints = JS.sB, chain, rel, pf9 ----
__global__ void k2_pose(const float* __restrict__ shp, const float* __restrict__ expr,
                        const float* __restrict__ pose, const float* __restrict__ JS,
                        float* __restrict__ betasF, float* __restrict__ pf9,
                        float* __restrict__ rel) {
    int b = blockIdx.x;
    int tt = threadIdx.x;
    __shared__ float sB[NBP];
    __shared__ float sJ[15];
    for (int l = tt; l < NBP; l += 64) {
        float val = 0.0f;
        if (l < 100) val = shp[b * 100 + l];
        else if (l < 150) val = expr[b * 50 + (l - 100)];
        else if (l == 150) val = 1.0f;   // picks up v_template / Jt columns
        sB[l] = val;
        betasF[b * NBP + l] = val;
    }
    __syncthreads();
    if (tt < 15) {
        float acc = 0.0f;
        const float* row = JS + tt * NBP;
        for (int l = 0; l < NBP; ++l) acc += row[l] * sB[l];
        sJ[tt] = acc;
    }
    __syncthreads();
    if (tt == 0) {
        float p[6];
#pragma unroll
        for (int i = 0; i < 6; i++) p[i] = pose[b * 6 + i];
        float R0[9], RJ[9];
        rodrigues3(p[0], p[1], p[2], R0);
        rodrigues3(p[3], p[4], p[5], RJ);
        float Jm[5][3];
#pragma unroll
        for (int jj = 0; jj < 5; jj++)
#pragma unroll
            for (int cc = 0; cc < 3; cc++) Jm[jj][cc] = sJ[jj * 3 + cc];
        float rj[5][3];
#pragma unroll
        for (int cc = 0; cc < 3; cc++) {
            rj[0][cc] = Jm[0][cc];
            rj[1][cc] = Jm[1][cc] - Jm[0][cc];
            rj[2][cc] = Jm[2][cc] - Jm[1][cc];
            rj[3][cc] = Jm[3][cc] - Jm[1][cc];
            rj[4][cc] = Jm[4][cc] - Jm[1][cc];
        }
        float tw[5][3];
#pragma unroll
        for (int cc = 0; cc < 3; cc++) tw[0][cc] = rj[0][cc];
#pragma unroll
        for (int cc = 0; cc < 3; cc++)
            tw[1][cc] = R0[cc * 3 + 0] * rj[1][0] + R0[cc * 3 + 1] * rj[1][1] + R0[cc * 3 + 2] * rj[1][2] + tw[0][cc];
#pragma unroll
        for (int jj = 2; jj < 5; jj++)
#pragma unroll
            for (int cc = 0; cc < 3; cc++)
                tw[jj][cc] = R0[cc * 3 + 0] * rj[jj][0] + R0[cc * 3 + 1] * rj[jj][1] + R0[cc * 3 + 2] * rj[jj][2] + tw[1][cc];
        float R2w[9];
#pragma unroll
        for (int r = 0; r < 3; r++)
#pragma unroll
            for (int cc = 0; cc < 3; cc++) {
                float a = 0.f;
#pragma unroll
                for (int k = 0; k < 3; k++) a += R0[r * 3 + k] * RJ[k * 3 + cc];
                R2w[r * 3 + cc] = a;
            }
        float* ro = rel + b * 80;
#pragma unroll
        for (int jj = 0; jj < 5; jj++) {
            const float* Rw = (jj == 2) ? R2w : R0;
#pragma unroll
            for (int rr = 0; rr < 3; rr++) {
                ro[jj * 16 + rr * 4 + 0] = Rw[rr * 3 + 0];
                ro[jj * 16 + rr * 4 + 1] = Rw[rr * 3 + 1];
                ro[jj * 16 + rr * 4 + 2] = Rw[rr * 3 + 2];
                float tj = Rw[rr * 3 + 0] * Jm[jj][0] + Rw[rr * 3 + 1] * Jm[jj][1] + Rw[rr * 3 + 2] * Jm[jj][2];
                ro[jj * 16 + rr * 4 + 3] = tw[jj][rr] - tj;
            }
            ro[jj * 16 + 12] = 0.f; ro[jj * 16 + 13] = 0.f; ro[jj * 16 + 14] = 0.f; ro[jj * 16 + 15] = 1.f;
        }
        float* pf = pf9 + b * 12;
#pragma unroll
        for (int e = 0; e < 9; e++) pf[e] = RJ[e] - ((e == 0 || e == 4 || e == 8) ? 1.f : 0.f);
        pf[9] = 0.f; pf[10] = 0.f; pf[11] = 0.f;
    }
}

// ---- K3: fused blendshape GEMM + pose blend + LBS, register-double-buffered sdp ----
__global__ void k3_main(const float* __restrict__ sdp, const float* __restrict__ pd,
                        const float* __restrict__ lw,
                        const float* __restrict__ betasF, const float* __restrict__ pf9,
                        const float* __restrict__ rel,
                        float* __restrict__ outv, float* __restrict__ outT) {
    __shared__ float sBet[BT][NBP];   // 9728 B
    __shared__ float sRel[BT][80];    // 5120 B
    __shared__ float sPf[BT][12];     // 768 B

    int tid = threadIdx.x;
    int v = blockIdx.x * 128 + tid;
    bool ok = v < VN;
    int vc = ok ? v : 0;
    int b0 = blockIdx.y * BT;

    for (int i = tid; i < BT * NBP; i += 128) {
        int bb = i / NBP, l = i - bb * NBP;
        sBet[bb][l] = betasF[(size_t)(b0 + bb) * NBP + l];
    }
    for (int i = tid; i < BT * 80; i += 128) {
        int bb = i / 80, e = i - bb * 80;
        sRel[bb][e] = rel[(size_t)(b0 + bb) * 80 + e];
    }
    for (int i = tid; i < BT * 12; i += 128) {
        int bb = i / 12, e = i - bb * 12;
        sPf[bb][e] = pf9[(size_t)(b0 + bb) * 12 + e];
    }
    __syncthreads();

    float acc[3][BT];
#pragma unroll
    for (int c = 0; c < 3; c++)
#pragma unroll
        for (int bb = 0; bb < BT; bb++) acc[c][bb] = 0.0f;

    const float* srow = sdp + (size_t)vc * 3 * NBP;

    // software pipeline: prefetch tile l0+8 while computing tile l0
    float4 nA0 = *(const float4*)(srow + 0);
    float4 nA1 = *(const float4*)(srow + 4);
    float4 nB0 = *(const float4*)(srow + NBP);
    float4 nB1 = *(const float4*)(srow + NBP + 4);
    float4 nC0 = *(const float4*)(srow + 2 * NBP);
    float4 nC1 = *(const float4*)(srow + 2 * NBP + 4);

#pragma unroll 1
    for (int l0 = 0; l0 < NBP; l0 += 8) {
        float4 a0 = nA0, a1 = nA1, bq0 = nB0, bq1 = nB1, cq0 = nC0, cq1 = nC1;
        int ln = (l0 + 8 < NBP) ? (l0 + 8) : 0;       // dummy (in-bounds) prefetch on last iter
        nA0 = *(const float4*)(srow + ln);
        nA1 = *(const float4*)(srow + ln + 4);
        nB0 = *(const float4*)(srow + NBP + ln);
        nB1 = *(const float4*)(srow + NBP + ln + 4);
        nC0 = *(const float4*)(srow + 2 * NBP + ln);
        nC1 = *(const float4*)(srow + 2 * NBP + ln + 4);

        float s0[8] = {a0.x, a0.y, a0.z, a0.w, a1.x, a1.y, a1.z, a1.w};
        float s1[8] = {bq0.x, bq0.y, bq0.z, bq0.w, bq1.x, bq1.y, bq1.z, bq1.w};
        float s2[8] = {cq0.x, cq0.y, cq0.z, cq0.w, cq1.x, cq1.y, cq1.z, cq1.w};
#pragma unroll
        for (int bb = 0; bb < BT; bb++) {
            const float4 be0 = *(const float4*)(&sBet[bb][l0]);
            const float4 be1 = *(const float4*)(&sBet[bb][l0 + 4]);
            float be[8] = {be0.x, be0.y, be0.z, be0.w, be1.x, be1.y, be1.z, be1.w};
#pragma unroll
            for (int k = 0; k < 8; k++) {
                acc[0][bb] += be[k] * s0[k];
                acc[1][bb] += be[k] * s1[k];
                acc[2][bb] += be[k] * s2[k];
            }
        }
    }

    if (!ok) return;

    float wj[5], pdv[9][3];
#pragma unroll
    for (int j = 0; j < 5; j++) wj[j] = lw[v * 5 + j];
#pragma unroll
    for (int k = 0; k < 9; k++)
#pragma unroll
        for (int c = 0; c < 3; c++) pdv[k][c] = pd[(size_t)(9 + k) * N3 + v * 3 + c];

#pragma unroll    // full unroll: acc must stay register-indexed
    for (int bb = 0; bb < BT; bb++) {
        int b = b0 + bb;
        float vp[3];
#pragma unroll
        for (int c = 0; c < 3; c++) {
            float x = acc[c][bb];                     // = v_shaped (template folded in)
#pragma unroll
            for (int k = 0; k < 9; k++) x += sPf[bb][k] * pdv[k][c];
            vp[c] = x;
        }
        float T[16];
#pragma unroll
        for (int e = 0; e < 16; e++) T[e] = 0.0f;
#pragma unroll
        for (int j = 0; j < 5; j++) {
            float w = wj[j];
            const float4* rj4 = (const float4*)(&sRel[bb][j * 16]);
            float4 r0 = rj4[0], r1 = rj4[1], r2 = rj4[2], r3 = rj4[3];
            T[0]  += w * r0.x;  T[1]  += w * r0.y;  T[2]  += w * r0.z;  T[3]  += w * r0.w;
            T[4]  += w * r1.x;  T[5]  += w * r1.y;  T[6]  += w * r1.z;  T[7]  += w * r1.w;
            T[8]  += w * r2.x;  T[9]  += w * r2.y;  T[10] += w * r2.z;  T[11] += w * r2.w;
            T[12] += w * r3.x;  T[13] += w * r3.y;  T[14] += w * r3.z;  T[15] += w * r3.w;
        }
        float vo[3];
#pragma unroll
        for (int rr = 0; rr < 3; rr++)
            vo[rr] = T[rr * 4 + 0] * vp[0] + T[rr * 4 + 1] * vp[1] + T[rr * 4 + 2] * vp[2] + T[rr * 4 + 3];

        size_t vbase = (size_t)b * VN + v;
        float* pv = outv + vbase * 3;
        pv[0] = vo[0];
        pv[1] = vo[1];
        pv[2] = vo[2];
        float4* pT = (float4*)(outT + vbase * 16);
        pT[0] = make_float4(T[0],  T[1],  T[2],  T[3]);
        pT[1] = make_float4(T[4],  T[5],  T[6],  T[7]);
        pT[2] = make_float4(T[8],  T[9],  T[10], T[11]);
        pT[3] = make_float4(T[12], T[13], T[14], T[15]);
    }
}

// ---------------- launch ----------------
extern "C" void kernel_launch(void* const* d_in, const int* in_sizes, int n_in,
                              void* d_out, int out_size, void* d_ws, size_t ws_size,
                              hipStream_t stream) {
    const float* shp  = (const float*)d_in[0];  // [1024,100]
    const float* expr = (const float*)d_in[1];  // [1024,50]
    const float* pose = (const float*)d_in[2];  // [1024,6]
    const float* vt   = (const float*)d_in[3];  // [5023,3]
    const float* sd   = (const float*)d_in[4];  // [5023,3,150]
    const float* pd   = (const float*)d_in[5];  // [36,15069]
    // d_in[6] = J_regressor [5,5023], d_in[7] = lbs_weights [5023,5]
    const float* jr   = (const float*)d_in[6];
    const float* lw   = (const float*)d_in[7];

    float* outv = (float*)d_out;
    float* outT = outv + (size_t)NBATCH * VN * 3;

    char* w = (char*)d_ws;
    const size_t SDP_B   = (size_t)N3 * NBP * 4;            // 9,161,952
    const size_t JS_B    = 15 * NBP * 4;                    // 9,120
    const size_t BETAS_B = (size_t)NBATCH * NBP * 4;        // 622,592
    const size_t PF9_B   = (size_t)NBATCH * 12 * 4;         // 49,152
    float* sdp    = (float*)w;
    float* JS     = (float*)(w + SDP_B);
    float* betasF = (float*)(w + SDP_B + JS_B);
    float* pf9    = (float*)(w + SDP_B + JS_B + BETAS_B);
    float* rel    = (float*)(w + SDP_B + JS_B + BETAS_B + PF9_B);

    k0_pad<<<(N3 * NBP + 255) / 256, 256, 0, stream>>>(sd, vt, sdp, JS);
    k1_js<<<dim3(15, (VN + K1_CHUNK - 1) / K1_CHUNK), 192, 0, stream>>>(jr, sdp, JS);
    k2_pose<<<NBATCH, 64, 0, stream>>>(shp, expr, pose, JS, betasF, pf9, rel);
    k3_main<<<dim3(40, NBATCH / BT), 128, 0, stream>>>(sdp, pd, lw, betasF, pf9, rel, outv, outT);
}